// Round 7
// baseline (607.280 us; speedup 1.0000x reference)
//
#include <hip/hip_runtime.h>
#include <hip/hip_cooperative_groups.h>
#include <math.h>

#pragma float_control(precise, on)

#define EPSF 1e-8f

namespace cg = cooperative_groups;

// R29: single cooperative dispatch (~30 us/dispatch overhead was the biggest
// remaining item: 2 dispatches ~= 60 us of 147) + conditional fallback ray.
// - mega_kernel (cooperative, grid = N = 2048 blocks = exactly 8 blocks/CU,
//   __launch_bounds__(256,8) forces VGPR<=64): tri prep -> knn (R27-verbatim
//   single-list; nc/v1/dfb stay in LDS) -> threadfence+grid.sync+threadfence
//   -> ray-a pass (coalesced tri streaming) -> ray-b pass ONLY if ray-a
//   missed (block-uniform; reference uses loc2 only where !hit1 => exact;
//   recomputed tvec/qvec/tq are the identical expressions => identical bits)
//   -> finalize (verbatim). No early returns before grid.sync (deadlock
//   audit); all __syncthreads block-uniform.
// - Fallback (attribute or launch-failure): R28 two-kernel path verbatim.

// ---------------------------------------------------------------------------
// Cooperative fused kernel. block = point. 256 threads = 4 waves.
// ---------------------------------------------------------------------------
__global__ void __launch_bounds__(256, 8) mega_kernel(
    const float* __restrict__ x, const float* __restrict__ verts,
    const float* __restrict__ vnorm, const int* __restrict__ faces,
    float* __restrict__ tri, float* __restrict__ out,
    int N, int V, int F) {
#pragma clang fp contract(off)
    const float M = 1e-5f;  // graze margin (R21-certified)
    int p = blockIdx.x;     // grid.x == N
    int tid = threadIdx.x;
    int wave = tid >> 6;
    int lane = tid & 63;

    __shared__ unsigned long long cand[32];
    __shared__ float bc[9];          // nc[0..2], v1[3..5], dfb[6..8]
    __shared__ unsigned int red[8];  // pass-a: [0..3], pass-b: [4..7]
    __shared__ unsigned int u1s, u2s, hflag;

    // ---------------- phase 0: triangle SoA prep (grid-strided) -----------
    for (int gt = p * 256 + tid; gt < F; gt += gridDim.x * 256) {
        int f0 = faces[gt * 3 + 0];
        int f1 = faces[gt * 3 + 1];
        int f2 = faces[gt * 3 + 2];
        float t0x = verts[f0 * 3 + 0], t0y = verts[f0 * 3 + 1], t0z = verts[f0 * 3 + 2];
        float ax = verts[f1 * 3 + 0], ay = verts[f1 * 3 + 1], az = verts[f1 * 3 + 2];
        float bx = verts[f2 * 3 + 0], by = verts[f2 * 3 + 1], bz = verts[f2 * 3 + 2];
        float4* t4 = (float4*)(tri + (size_t)gt * 12);
        t4[0] = make_float4(t0x, t0y, t0z, ax - t0x);
        t4[1] = make_float4(ay - t0y, az - t0z, bx - t0x, by - t0y);
        t4[2] = make_float4(bz - t0z, 0.f, 0.f, 0.f);
    }

    // ---------------- phase 1: KNN (K=8), R27-verbatim single-list --------
    float xx = x[p * 3 + 0];
    float xy = x[p * 3 + 1];
    float xz = x[p * 3 + 2];

    unsigned long long key[8];
#pragma unroll
    for (int i = 0; i < 8; ++i) key[i] = ~0ULL;

    for (int v = tid; v < V; v += 256) {
        float dx = xx - verts[v * 3 + 0];
        float dy = xy - verts[v * 3 + 1];
        float dz = xz - verts[v * 3 + 2];
        float d2 = ((dx * dx) + (dy * dy)) + (dz * dz);
        unsigned long long k =
            (((unsigned long long)__float_as_uint(d2)) << 32) | (unsigned int)v;
        if (k < key[7]) {
            key[7] = k;
#pragma unroll
            for (int j = 7; j > 0; --j) {
                if (key[j] < key[j - 1]) {
                    unsigned long long t = key[j];
                    key[j] = key[j - 1];
                    key[j - 1] = t;
                }
            }
        }
    }

#pragma unroll
    for (int j = 0; j < 8; ++j) {
        unsigned long long m = key[0];
#pragma unroll
        for (int s = 1; s < 64; s <<= 1) {
            unsigned long long o = __shfl_xor(m, s, 64);
            if (o < m) m = o;
        }
        if (key[0] == m) {
#pragma unroll
            for (int t = 0; t < 7; ++t) key[t] = key[t + 1];
            key[7] = ~0ULL;
        }
        if (lane == 0) cand[wave * 8 + j] = m;
    }
    __syncthreads();

    if (wave == 0) {
        unsigned long long c0 = (lane < 32) ? cand[lane] : ~0ULL;
        unsigned long long sel[8];
#pragma unroll
        for (int j = 0; j < 8; ++j) {
            unsigned long long m = c0;
#pragma unroll
            for (int s = 1; s < 64; s <<= 1) {
                unsigned long long o = __shfl_xor(m, s, 64);
                if (o < m) m = o;
            }
            if (c0 == m) c0 = ~0ULL;
            sel[j] = m;
        }

        if (lane == 0) {
            // lane-0 tail: verbatim (bit-identical arithmetic order)
            float invk[8];
            float nsx = 0.f, nsy = 0.f, nsz = 0.f;
#pragma unroll
            for (int j = 0; j < 8; ++j) {
                int id = (int)(sel[j] & 0xffffffffu);
                float d2 = __uint_as_float((unsigned int)(sel[j] >> 32));
                float inv = 1.0f / fmaxf(d2, EPSF);
                invk[j] = inv;
                nsx = nsx + vnorm[id * 3 + 0] * inv;
                nsy = nsy + vnorm[id * 3 + 1] * inv;
                nsz = nsz + vnorm[id * 3 + 2] * inv;
            }
            float Wsum = ((invk[0] + invk[1]) + (invk[2] + invk[3])) +
                         ((invk[4] + invk[5]) + (invk[6] + invk[7]));

            int id0 = (int)(sel[0] & 0xffffffffu);
            float v1x = verts[id0 * 3 + 0];
            float v1y = verts[id0 * 3 + 1];
            float v1z = verts[id0 * 3 + 2];

            float dxv = xx - v1x, dyv = xy - v1y, dzv = xz - v1z;
            float d2v1 = fmaxf(((dxv * dxv) + (dyv * dyv)) + (dzv * dzv), EPSF);
            float den = 0.01f * d2v1;
            float tdx = dxv / den, tdy = dyv / den, tdz = dzv / den;

            float W = Wsum + 100.0f;
            float ntx = (nsx + tdx) / W;
            float nty = (nsy + tdy) / W;
            float ntz = (nsz + tdz) / W;
            float nrm = sqrtf(((ntx * ntx) + (nty * nty)) + (ntz * ntz)) + 1e-8f;
            bc[0] = ntx / nrm; bc[1] = nty / nrm; bc[2] = ntz / nrm;
            bc[3] = v1x; bc[4] = v1y; bc[5] = v1z;

            float fx = v1x - xx, fy = v1y - xy, fz = v1z - xz;
            float fn = sqrtf(((fx * fx) + (fy * fy)) + (fz * fz)) + 1e-8f;
            bc[6] = fx / fn; bc[7] = fy / fn; bc[8] = fz / fn;
        }
    }
    __syncthreads();

    // ---------------- grid-wide barrier (tri ready everywhere) ------------
    __threadfence();
    cg::this_grid().sync();
    __threadfence();

    float ncx = bc[0], ncy = bc[1], ncz = bc[2];
    float dbx = bc[6], dby = bc[7], dbz = bc[8];
    float dax = -ncx, day = -ncy, daz = -ncz;
    const float INF = __uint_as_float(0x7f800000u);

    // ---------------- phase 2a: ray-a (-nc) over streamed tri -------------
    float tba = INF;
    for (int fi = tid; fi < F; fi += 256) {
        const float4 A = *(const float4*)(tri + (size_t)fi * 12);
        const float4 B = *(const float4*)(tri + (size_t)fi * 12 + 4);
        const float4 C = *(const float4*)(tri + (size_t)fi * 12 + 8);
        float e1x = A.w, e1y = B.x, e1z = B.y;
        float e2x = B.z, e2y = B.w, e2z = C.x;

        float tvx = xx - A.x;
        float tvy = xy - A.y;
        float tvz = xz - A.z;
        float qx = (tvy * e1z) - (tvz * e1y);
        float qy = (tvz * e1x) - (tvx * e1z);
        float qz = (tvx * e1y) - (tvy * e1x);
        float tq = ((e2x * qx) + (e2y * qy)) + (e2z * qz);

        float px = (day * e2z) - (daz * e2y);
        float py = (daz * e2x) - (dax * e2z);
        float pz = (dax * e2y) - (day * e2x);
        float det = ((e1x * px) + (e1y * py)) + (e1z * pz);
        bool ok = fabsf(det) > EPSF;
        float inv = ok ? (1.0f / det) : 0.0f;
        float u = (((tvx * px) + (tvy * py)) + (tvz * pz)) * inv;
        float v = (((dax * qx) + (day * qy)) + (daz * qz)) * inv;
        float t = tq * inv;
        bool valid = ok && (u >= -M) && (v >= -M) && ((u + v) <= 1.0f + M) && (t > EPSF);
        tba = (valid && t < tba) ? t : tba;
    }

    {
        unsigned int ma = __float_as_uint(tba);
#pragma unroll
        for (int s = 1; s < 64; s <<= 1) {
            unsigned int oa = __shfl_xor(ma, s, 64);
            if (oa < ma) ma = oa;
        }
        if (lane == 0) red[wave] = ma;
    }
    __syncthreads();
    if (tid == 0) {
        unsigned int u1 = min(min(red[0], red[1]), min(red[2], red[3]));
        u1s = u1;
        hflag = (u1 < 0x7f800000u) ? 1u : 0u;
    }
    __syncthreads();

    // ---------------- phase 2b: ray-b (dfb) only if ray-a missed ----------
    if (hflag == 0u) {  // block-uniform
        float tbb = INF;
        for (int fi = tid; fi < F; fi += 256) {
            const float4 A = *(const float4*)(tri + (size_t)fi * 12);
            const float4 B = *(const float4*)(tri + (size_t)fi * 12 + 4);
            const float4 C = *(const float4*)(tri + (size_t)fi * 12 + 8);
            float e1x = A.w, e1y = B.x, e1z = B.y;
            float e2x = B.z, e2y = B.w, e2z = C.x;

            // identical expressions/order as pass a => identical bits
            float tvx = xx - A.x;
            float tvy = xy - A.y;
            float tvz = xz - A.z;
            float qx = (tvy * e1z) - (tvz * e1y);
            float qy = (tvz * e1x) - (tvx * e1z);
            float qz = (tvx * e1y) - (tvy * e1x);
            float tq = ((e2x * qx) + (e2y * qy)) + (e2z * qz);

            float px = (dby * e2z) - (dbz * e2y);
            float py = (dbz * e2x) - (dbx * e2z);
            float pz = (dbx * e2y) - (dby * e2x);
            float det = ((e1x * px) + (e1y * py)) + (e1z * pz);
            bool ok = fabsf(det) > EPSF;
            float inv = ok ? (1.0f / det) : 0.0f;
            float u = (((tvx * px) + (tvy * py)) + (tvz * pz)) * inv;
            float v = (((dbx * qx) + (dby * qy)) + (dbz * qz)) * inv;
            float t = tq * inv;
            bool valid = ok && (u >= -M) && (v >= -M) && ((u + v) <= 1.0f + M) && (t > EPSF);
            tbb = (valid && t < tbb) ? t : tbb;
        }
        unsigned int mb = __float_as_uint(tbb);
#pragma unroll
        for (int s = 1; s < 64; s <<= 1) {
            unsigned int ob = __shfl_xor(mb, s, 64);
            if (ob < mb) mb = ob;
        }
        if (lane == 0) red[4 + wave] = mb;
        __syncthreads();
        if (tid == 0)
            u2s = min(min(red[4], red[5]), min(red[6], red[7]));
    }

    // ---------------- phase 3: finalize (verbatim), thread 0 --------------
    if (tid == 0) {
        float t1 = __uint_as_float(u1s);
        bool h1 = t1 < INF;
        float t2 = h1 ? INF : __uint_as_float(u2s);
        bool h2 = t2 < INF;

        float xcx, xcy, xcz;
        if (h1) {
            xcx = xx + ((-ncx) * t1);
            xcy = xy + ((-ncy) * t1);
            xcz = xz + ((-ncz) * t1);
        } else if (h2) {
            xcx = xx + (dbx * t2);
            xcy = xy + (dby * t2);
            xcz = xz + (dbz * t2);
        } else {
            xcx = bc[3]; xcy = bc[4]; xcz = bc[5];
        }
        float s = (((xx - xcx) * ncx) + ((xy - xcy) * ncy)) + ((xz - xcz) * ncz);

        out[p * 3 + 0] = xcx;
        out[p * 3 + 1] = xcy;
        out[p * 3 + 2] = xcz;
        out[3 * N + p] = s;
        out[4 * N + p * 3 + 0] = ncx;
        out[4 * N + p * 3 + 1] = ncy;
        out[4 * N + p * 3 + 2] = ncz;
    }
}

// ===========================================================================
// Fallback path: R28 two-kernel pipeline, verbatim.
// ===========================================================================
__global__ void __launch_bounds__(256) knn_prep_kernel(
    const float* __restrict__ x, const float* __restrict__ verts,
    const float* __restrict__ vnorm, const int* __restrict__ faces,
    float* __restrict__ tri, float* __restrict__ ncw,
    float* __restrict__ v1w, float* __restrict__ dfbw,
    int N, int V, int F) {
#pragma clang fp contract(off)
    int p = blockIdx.x;
    int tid = threadIdx.x;
    int wave = tid >> 6;
    int lane = tid & 63;
    if (p >= N) return;

    int gt = p * 256 + tid;
    if (gt < F) {
        int f0 = faces[gt * 3 + 0];
        int f1 = faces[gt * 3 + 1];
        int f2 = faces[gt * 3 + 2];
        float t0x = verts[f0 * 3 + 0], t0y = verts[f0 * 3 + 1], t0z = verts[f0 * 3 + 2];
        float ax = verts[f1 * 3 + 0], ay = verts[f1 * 3 + 1], az = verts[f1 * 3 + 2];
        float bx = verts[f2 * 3 + 0], by = verts[f2 * 3 + 1], bz = verts[f2 * 3 + 2];
        float4* t4 = (float4*)(tri + (size_t)gt * 12);
        t4[0] = make_float4(t0x, t0y, t0z, ax - t0x);
        t4[1] = make_float4(ay - t0y, az - t0z, bx - t0x, by - t0y);
        t4[2] = make_float4(bz - t0z, 0.f, 0.f, 0.f);
    }

    float xx = x[p * 3 + 0];
    float xy = x[p * 3 + 1];
    float xz = x[p * 3 + 2];

    unsigned long long key[8];
#pragma unroll
    for (int i = 0; i < 8; ++i) key[i] = ~0ULL;

    for (int v = tid; v < V; v += 256) {
        float dx = xx - verts[v * 3 + 0];
        float dy = xy - verts[v * 3 + 1];
        float dz = xz - verts[v * 3 + 2];
        float d2 = ((dx * dx) + (dy * dy)) + (dz * dz);
        unsigned long long k =
            (((unsigned long long)__float_as_uint(d2)) << 32) | (unsigned int)v;
        if (k < key[7]) {
            key[7] = k;
#pragma unroll
            for (int j = 7; j > 0; --j) {
                if (key[j] < key[j - 1]) {
                    unsigned long long t = key[j];
                    key[j] = key[j - 1];
                    key[j - 1] = t;
                }
            }
        }
    }

    __shared__ unsigned long long cand[32];
#pragma unroll
    for (int j = 0; j < 8; ++j) {
        unsigned long long m = key[0];
#pragma unroll
        for (int s = 1; s < 64; s <<= 1) {
            unsigned long long o = __shfl_xor(m, s, 64);
            if (o < m) m = o;
        }
        if (key[0] == m) {
#pragma unroll
            for (int t = 0; t < 7; ++t) key[t] = key[t + 1];
            key[7] = ~0ULL;
        }
        if (lane == 0) cand[wave * 8 + j] = m;
    }
    __syncthreads();
    if (wave != 0) return;

    unsigned long long c0 = (lane < 32) ? cand[lane] : ~0ULL;
    unsigned long long sel[8];
#pragma unroll
    for (int j = 0; j < 8; ++j) {
        unsigned long long m = c0;
#pragma unroll
        for (int s = 1; s < 64; s <<= 1) {
            unsigned long long o = __shfl_xor(m, s, 64);
            if (o < m) m = o;
        }
        if (c0 == m) c0 = ~0ULL;
        sel[j] = m;
    }
    if (lane != 0) return;

    float invk[8];
    float nsx = 0.f, nsy = 0.f, nsz = 0.f;
#pragma unroll
    for (int j = 0; j < 8; ++j) {
        int id = (int)(sel[j] & 0xffffffffu);
        float d2 = __uint_as_float((unsigned int)(sel[j] >> 32));
        float inv = 1.0f / fmaxf(d2, EPSF);
        invk[j] = inv;
        nsx = nsx + vnorm[id * 3 + 0] * inv;
        nsy = nsy + vnorm[id * 3 + 1] * inv;
        nsz = nsz + vnorm[id * 3 + 2] * inv;
    }
    float Wsum = ((invk[0] + invk[1]) + (invk[2] + invk[3])) +
                 ((invk[4] + invk[5]) + (invk[6] + invk[7]));

    int id0 = (int)(sel[0] & 0xffffffffu);
    float v1x = verts[id0 * 3 + 0];
    float v1y = verts[id0 * 3 + 1];
    float v1z = verts[id0 * 3 + 2];

    float dxv = xx - v1x, dyv = xy - v1y, dzv = xz - v1z;
    float d2v1 = fmaxf(((dxv * dxv) + (dyv * dyv)) + (dzv * dzv), EPSF);
    float den = 0.01f * d2v1;
    float tdx = dxv / den, tdy = dyv / den, tdz = dzv / den;

    float W = Wsum + 100.0f;
    float ntx = (nsx + tdx) / W;
    float nty = (nsy + tdy) / W;
    float ntz = (nsz + tdz) / W;
    float nrm = sqrtf(((ntx * ntx) + (nty * nty)) + (ntz * ntz)) + 1e-8f;
    float ncx = ntx / nrm, ncy = nty / nrm, ncz = ntz / nrm;

    float fx = v1x - xx, fy = v1y - xy, fz = v1z - xz;
    float fn = sqrtf(((fx * fx) + (fy * fy)) + (fz * fz)) + 1e-8f;
    fx = fx / fn; fy = fy / fn; fz = fz / fn;

    ncw[p * 3 + 0] = ncx; ncw[p * 3 + 1] = ncy; ncw[p * 3 + 2] = ncz;
    v1w[p * 3 + 0] = v1x; v1w[p * 3 + 1] = v1y; v1w[p * 3 + 2] = v1z;
    dfbw[p * 3 + 0] = fx; dfbw[p * 3 + 1] = fy; dfbw[p * 3 + 2] = fz;
}

__global__ void __launch_bounds__(256) ray_fin_kernel(
    const float* __restrict__ x, const float* __restrict__ tri,
    const float* __restrict__ ncw, const float* __restrict__ v1w,
    const float* __restrict__ dfbw, float* __restrict__ out, int N, int F) {
#pragma clang fp contract(off)
    const float M = 1e-5f;
    __shared__ unsigned int red[8];
    int p = blockIdx.x;
    int tid = threadIdx.x;
    int wave = tid >> 6;
    int lane = tid & 63;
    if (p >= N) return;

    float xx = x[p * 3 + 0];
    float xy = x[p * 3 + 1];
    float xz = x[p * 3 + 2];
    float ncx = ncw[p * 3 + 0], ncy = ncw[p * 3 + 1], ncz = ncw[p * 3 + 2];
    float dbx = dfbw[p * 3 + 0], dby = dfbw[p * 3 + 1], dbz = dfbw[p * 3 + 2];
    float dax = -ncx, day = -ncy, daz = -ncz;

    const float INF = __uint_as_float(0x7f800000u);
    float tba = INF, tbb = INF;
    for (int fi = tid; fi < F; fi += 256) {
        const float4 A = *(const float4*)(tri + (size_t)fi * 12);
        const float4 B = *(const float4*)(tri + (size_t)fi * 12 + 4);
        const float4 C = *(const float4*)(tri + (size_t)fi * 12 + 8);
        float e1x = A.w, e1y = B.x, e1z = B.y;
        float e2x = B.z, e2y = B.w, e2z = C.x;

        float tvx = xx - A.x;
        float tvy = xy - A.y;
        float tvz = xz - A.z;
        float qx = (tvy * e1z) - (tvz * e1y);
        float qy = (tvz * e1x) - (tvx * e1z);
        float qz = (tvx * e1y) - (tvy * e1x);
        float tq = ((e2x * qx) + (e2y * qy)) + (e2z * qz);

        {
            float px = (day * e2z) - (daz * e2y);
            float py = (daz * e2x) - (dax * e2z);
            float pz = (dax * e2y) - (day * e2x);
            float det = ((e1x * px) + (e1y * py)) + (e1z * pz);
            bool ok = fabsf(det) > EPSF;
            float inv = ok ? (1.0f / det) : 0.0f;
            float u = (((tvx * px) + (tvy * py)) + (tvz * pz)) * inv;
            float v = (((dax * qx) + (day * qy)) + (daz * qz)) * inv;
            float t = tq * inv;
            bool valid = ok && (u >= -M) && (v >= -M) && ((u + v) <= 1.0f + M) && (t > EPSF);
            tba = (valid && t < tba) ? t : tba;
        }
        {
            float px = (dby * e2z) - (dbz * e2y);
            float py = (dbz * e2x) - (dbx * e2z);
            float pz = (dbx * e2y) - (dby * e2x);
            float det = ((e1x * px) + (e1y * py)) + (e1z * pz);
            bool ok = fabsf(det) > EPSF;
            float inv = ok ? (1.0f / det) : 0.0f;
            float u = (((tvx * px) + (tvy * py)) + (tvz * pz)) * inv;
            float v = (((dbx * qx) + (dby * qy)) + (dbz * qz)) * inv;
            float t = tq * inv;
            bool valid = ok && (u >= -M) && (v >= -M) && ((u + v) <= 1.0f + M) && (t > EPSF);
            tbb = (valid && t < tbb) ? t : tbb;
        }
    }

    unsigned int ma = __float_as_uint(tba);
    unsigned int mb = __float_as_uint(tbb);
#pragma unroll
    for (int s = 1; s < 64; s <<= 1) {
        unsigned int oa = __shfl_xor(ma, s, 64);
        if (oa < ma) ma = oa;
        unsigned int ob = __shfl_xor(mb, s, 64);
        if (ob < mb) mb = ob;
    }
    if (lane == 0) { red[wave * 2 + 0] = ma; red[wave * 2 + 1] = mb; }
    __syncthreads();
    if (tid != 0) return;

    unsigned int u1 = min(min(red[0], red[2]), min(red[4], red[6]));
    unsigned int u2 = min(min(red[1], red[3]), min(red[5], red[7]));
    float t1 = __uint_as_float(u1);
    float t2 = __uint_as_float(u2);
    bool h1 = t1 < INF;
    bool h2 = t2 < INF;

    float xcx, xcy, xcz;
    if (h1) {
        xcx = xx + ((-ncx) * t1);
        xcy = xy + ((-ncy) * t1);
        xcz = xz + ((-ncz) * t1);
    } else if (h2) {
        xcx = xx + (dbx * t2);
        xcy = xy + (dby * t2);
        xcz = xz + (dbz * t2);
    } else {
        xcx = v1w[p * 3 + 0]; xcy = v1w[p * 3 + 1]; xcz = v1w[p * 3 + 2];
    }
    float s = (((xx - xcx) * ncx) + ((xy - xcy) * ncy)) + ((xz - xcz) * ncz);

    out[p * 3 + 0] = xcx;
    out[p * 3 + 1] = xcy;
    out[p * 3 + 2] = xcz;
    out[3 * N + p] = s;
    out[4 * N + p * 3 + 0] = ncx;
    out[4 * N + p * 3 + 1] = ncy;
    out[4 * N + p * 3 + 2] = ncz;
}

// ---------------------------------------------------------------------------
extern "C" void kernel_launch(void* const* d_in, const int* in_sizes, int n_in,
                              void* d_out, int out_size, void* d_ws, size_t ws_size,
                              hipStream_t stream) {
    const float* x     = (const float*)d_in[0];
    const float* verts = (const float*)d_in[1];
    const float* vnorm = (const float*)d_in[2];
    const int*   faces = (const int*)d_in[3];
    int N = in_sizes[0] / 3;
    int V = in_sizes[1] / 3;
    int F = in_sizes[3] / 3;

    float* tri  = (float*)d_ws;          // F*12 floats (16B-aligned AoS)
    float* ncw  = tri + (size_t)F * 12;  // 3*N (fallback only)
    float* v1w  = ncw + 3 * N;           // 3*N (fallback only)
    float* dfbw = v1w + 3 * N;           // 3*N (fallback only)
    float* outf = (float*)d_out;

    static int coop = -1;
    if (coop < 0) {
        int dev = 0, val = 0;
        hipGetDevice(&dev);
        hipDeviceGetAttribute(&val, hipDeviceAttributeCooperativeLaunch, dev);
        coop = val;
    }

    bool done = false;
    if (coop == 1) {
        void* args[] = {(void*)&x, (void*)&verts, (void*)&vnorm, (void*)&faces,
                        (void*)&tri, (void*)&outf, (void*)&N, (void*)&V, (void*)&F};
        hipError_t e = hipLaunchCooperativeKernel(
            (const void*)mega_kernel, dim3(N), dim3(256), args, 0u, stream);
        done = (e == hipSuccess);
    }
    if (!done) {
        hipLaunchKernelGGL(knn_prep_kernel, dim3(N), dim3(256), 0, stream,
                           x, verts, vnorm, faces, tri, ncw, v1w, dfbw, N, V, F);
        hipLaunchKernelGGL(ray_fin_kernel, dim3(N), dim3(256), 0, stream,
                           x, tri, ncw, v1w, dfbw, outf, N, F);
    }
}

// Round 8
// 140.322 us; speedup vs baseline: 4.3278x; 4.3278x over previous
//
#include <hip/hip_runtime.h>
#include <math.h>

#pragma float_control(precise, on)

#define EPSF 1e-8f

// R30: R28 two-dispatch chassis + conditional fallback ray.
// R29 post-mortem: cooperative grid.sync() cost ~450-500us (VALUBusy 10.8%)
// — reverted. ray_fin is VALU-bound (83% busy); the reference consumes loc2
// only where hit1 is false, so ray-b is now a block-uniform conditional
// second pass that runs only when ray-a found no hit. Pass-A/B arithmetic
// is the R28 fused loop's per-ray ops verbatim (shared-origin terms
// recomputed with identical expressions/order => identical bits).

// ---------------------------------------------------------------------------
// KNN (K=8) + coarse normal + triangle SoA prep. 256 threads = 4 waves/point.
// ---------------------------------------------------------------------------
__global__ void __launch_bounds__(256) knn_prep_kernel(
    const float* __restrict__ x, const float* __restrict__ verts,
    const float* __restrict__ vnorm, const int* __restrict__ faces,
    float* __restrict__ tri, float* __restrict__ ncw,
    float* __restrict__ v1w, float* __restrict__ dfbw,
    int N, int V, int F) {
#pragma clang fp contract(off)
    int p = blockIdx.x;
    int tid = threadIdx.x;
    int wave = tid >> 6;
    int lane = tid & 63;
    if (p >= N) return;

    // triangle prep: global thread gt handles triangle gt (blocks 0..31)
    int gt = p * 256 + tid;
    if (gt < F) {
        int f0 = faces[gt * 3 + 0];
        int f1 = faces[gt * 3 + 1];
        int f2 = faces[gt * 3 + 2];
        float t0x = verts[f0 * 3 + 0], t0y = verts[f0 * 3 + 1], t0z = verts[f0 * 3 + 2];
        float ax = verts[f1 * 3 + 0], ay = verts[f1 * 3 + 1], az = verts[f1 * 3 + 2];
        float bx = verts[f2 * 3 + 0], by = verts[f2 * 3 + 1], bz = verts[f2 * 3 + 2];
        float4* t4 = (float4*)(tri + (size_t)gt * 12);
        t4[0] = make_float4(t0x, t0y, t0z, ax - t0x);
        t4[1] = make_float4(ay - t0y, az - t0z, bx - t0x, by - t0y);
        t4[2] = make_float4(bz - t0z, 0.f, 0.f, 0.f);
    }

    float xx = x[p * 3 + 0];
    float xy = x[p * 3 + 1];
    float xz = x[p * 3 + 2];

    unsigned long long ka[8], kb[8];
#pragma unroll
    for (int i = 0; i < 8; ++i) { ka[i] = ~0ULL; kb[i] = ~0ULL; }

    // dual-list scan: vertex va -> list A, vertex vb = va+256 -> list B.
    for (int va = tid; va < V; va += 512) {
        int vb = va + 256;
        bool hasB = vb < V;

        float avx = verts[va * 3 + 0];
        float avy = verts[va * 3 + 1];
        float avz = verts[va * 3 + 2];
        float bvx = 0.f, bvy = 0.f, bvz = 0.f;
        if (hasB) {
            bvx = verts[vb * 3 + 0];
            bvy = verts[vb * 3 + 1];
            bvz = verts[vb * 3 + 2];
        }

        float dxa = xx - avx, dya = xy - avy, dza = xz - avz;
        float d2a = ((dxa * dxa) + (dya * dya)) + (dza * dza);
        unsigned long long kA =
            (((unsigned long long)__float_as_uint(d2a)) << 32) | (unsigned int)va;
        if (kA < ka[7]) {
            ka[7] = kA;
#pragma unroll
            for (int j = 7; j > 0; --j) {
                if (ka[j] < ka[j - 1]) {
                    unsigned long long t = ka[j];
                    ka[j] = ka[j - 1];
                    ka[j - 1] = t;
                }
            }
        }

        if (hasB) {
            float dxb = xx - bvx, dyb = xy - bvy, dzb = xz - bvz;
            float d2b = ((dxb * dxb) + (dyb * dyb)) + (dzb * dzb);
            unsigned long long kB =
                (((unsigned long long)__float_as_uint(d2b)) << 32) | (unsigned int)vb;
            if (kB < kb[7]) {
                kb[7] = kB;
#pragma unroll
                for (int j = 7; j > 0; --j) {
                    if (kb[j] < kb[j - 1]) {
                        unsigned long long t = kb[j];
                        kb[j] = kb[j - 1];
                        kb[j - 1] = t;
                    }
                }
            }
        }
    }

    // per-wave exact top-8 extraction over the dual lists
    unsigned long long wsel[8];
#pragma unroll
    for (int j = 0; j < 8; ++j) {
        unsigned long long c = (ka[0] < kb[0]) ? ka[0] : kb[0];
        unsigned long long m = c;
#pragma unroll
        for (int s = 1; s < 64; s <<= 1) {
            unsigned long long o = __shfl_xor(m, s, 64);
            if (o < m) m = o;
        }
        if (c == m) {  // unique keys: exactly one lane pops
            if (ka[0] == m) {
#pragma unroll
                for (int t = 0; t < 7; ++t) ka[t] = ka[t + 1];
                ka[7] = ~0ULL;
            } else {
#pragma unroll
                for (int t = 0; t < 7; ++t) kb[t] = kb[t + 1];
                kb[7] = ~0ULL;
            }
        }
        wsel[j] = m;
    }

    __shared__ unsigned long long cand[32];
    if (lane == 0) {
#pragma unroll
        for (int j = 0; j < 8; ++j) cand[wave * 8 + j] = wsel[j];
    }
    __syncthreads();
    if (wave != 0) return;

    // wave 0 merges 32 candidates -> global top-8 (exact: keys unique)
    unsigned long long c0 = (lane < 32) ? cand[lane] : ~0ULL;
    unsigned long long sel[8];
#pragma unroll
    for (int j = 0; j < 8; ++j) {
        unsigned long long m = c0;
#pragma unroll
        for (int s = 1; s < 64; s <<= 1) {
            unsigned long long o = __shfl_xor(m, s, 64);
            if (o < m) m = o;
        }
        if (c0 == m) c0 = ~0ULL;
        sel[j] = m;
    }

    if (lane != 0) return;

    // lane-0 tail: verbatim (bit-identical arithmetic order)
    float invk[8];
    float nsx = 0.f, nsy = 0.f, nsz = 0.f;
#pragma unroll
    for (int j = 0; j < 8; ++j) {
        int id = (int)(sel[j] & 0xffffffffu);
        float d2 = __uint_as_float((unsigned int)(sel[j] >> 32));
        float inv = 1.0f / fmaxf(d2, EPSF);
        invk[j] = inv;
        nsx = nsx + vnorm[id * 3 + 0] * inv;
        nsy = nsy + vnorm[id * 3 + 1] * inv;
        nsz = nsz + vnorm[id * 3 + 2] * inv;
    }
    float Wsum = ((invk[0] + invk[1]) + (invk[2] + invk[3])) +
                 ((invk[4] + invk[5]) + (invk[6] + invk[7]));

    int id0 = (int)(sel[0] & 0xffffffffu);
    float v1x = verts[id0 * 3 + 0];
    float v1y = verts[id0 * 3 + 1];
    float v1z = verts[id0 * 3 + 2];

    float dxv = xx - v1x, dyv = xy - v1y, dzv = xz - v1z;
    float d2v1 = fmaxf(((dxv * dxv) + (dyv * dyv)) + (dzv * dzv), EPSF);
    float den = 0.01f * d2v1;
    float tdx = dxv / den, tdy = dyv / den, tdz = dzv / den;

    float W = Wsum + 100.0f;
    float ntx = (nsx + tdx) / W;
    float nty = (nsy + tdy) / W;
    float ntz = (nsz + tdz) / W;
    float nrm = sqrtf(((ntx * ntx) + (nty * nty)) + (ntz * ntz)) + 1e-8f;
    float ncx = ntx / nrm, ncy = nty / nrm, ncz = ntz / nrm;

    float fx = v1x - xx, fy = v1y - xy, fz = v1z - xz;
    float fn = sqrtf(((fx * fx) + (fy * fy)) + (fz * fz)) + 1e-8f;
    fx = fx / fn; fy = fy / fn; fz = fz / fn;

    ncw[p * 3 + 0] = ncx; ncw[p * 3 + 1] = ncy; ncw[p * 3 + 2] = ncz;
    v1w[p * 3 + 0] = v1x; v1w[p * 3 + 1] = v1y; v1w[p * 3 + 2] = v1z;
    dfbw[p * 3 + 0] = fx; dfbw[p * 3 + 1] = fy; dfbw[p * 3 + 2] = fz;
}

// ---------------------------------------------------------------------------
// ray + reduce + finalize: block = point. Pass A = ray-a (-nc) only;
// pass B = ray-b (dfb), run only if ray-a missed (block-uniform).
// Streams the precomputed tri buffer (coalesced float4 x3, L2-resident).
// ---------------------------------------------------------------------------
__global__ void __launch_bounds__(256) ray_fin_kernel(
    const float* __restrict__ x, const float* __restrict__ tri,
    const float* __restrict__ ncw, const float* __restrict__ v1w,
    const float* __restrict__ dfbw, float* __restrict__ out, int N, int F) {
#pragma clang fp contract(off)
    const float M = 1e-5f;  // graze margin (R21-certified)
    __shared__ unsigned int red[4];
    __shared__ unsigned int u1s, u2s, hflag;
    int p = blockIdx.x;
    int tid = threadIdx.x;
    int wave = tid >> 6;
    int lane = tid & 63;
    if (p >= N) return;

    float xx = x[p * 3 + 0];
    float xy = x[p * 3 + 1];
    float xz = x[p * 3 + 2];
    float ncx = ncw[p * 3 + 0], ncy = ncw[p * 3 + 1], ncz = ncw[p * 3 + 2];
    float dbx = dfbw[p * 3 + 0], dby = dfbw[p * 3 + 1], dbz = dfbw[p * 3 + 2];
    float dax = -ncx, day = -ncy, daz = -ncz;

    const float INF = __uint_as_float(0x7f800000u);

    // -------- pass A: ray-a (-nc) --------
    float tba = INF;
    for (int fi = tid; fi < F; fi += 256) {
        const float4 A = *(const float4*)(tri + (size_t)fi * 12);
        const float4 B = *(const float4*)(tri + (size_t)fi * 12 + 4);
        const float4 C = *(const float4*)(tri + (size_t)fi * 12 + 8);
        float e1x = A.w, e1y = B.x, e1z = B.y;
        float e2x = B.z, e2y = B.w, e2z = C.x;

        float tvx = xx - A.x;
        float tvy = xy - A.y;
        float tvz = xz - A.z;
        float qx = (tvy * e1z) - (tvz * e1y);
        float qy = (tvz * e1x) - (tvx * e1z);
        float qz = (tvx * e1y) - (tvy * e1x);
        float tq = ((e2x * qx) + (e2y * qy)) + (e2z * qz);

        float px = (day * e2z) - (daz * e2y);
        float py = (daz * e2x) - (dax * e2z);
        float pz = (dax * e2y) - (day * e2x);
        float det = ((e1x * px) + (e1y * py)) + (e1z * pz);
        bool ok = fabsf(det) > EPSF;
        float inv = ok ? (1.0f / det) : 0.0f;
        float u = (((tvx * px) + (tvy * py)) + (tvz * pz)) * inv;
        float v = (((dax * qx) + (day * qy)) + (daz * qz)) * inv;
        float t = tq * inv;
        bool valid = ok && (u >= -M) && (v >= -M) && ((u + v) <= 1.0f + M) && (t > EPSF);
        tba = (valid && t < tba) ? t : tba;
    }

    {
        unsigned int ma = __float_as_uint(tba);
#pragma unroll
        for (int s = 1; s < 64; s <<= 1) {
            unsigned int oa = __shfl_xor(ma, s, 64);
            if (oa < ma) ma = oa;
        }
        if (lane == 0) red[wave] = ma;
    }
    __syncthreads();
    if (tid == 0) {
        unsigned int u1 = min(min(red[0], red[1]), min(red[2], red[3]));
        u1s = u1;
        hflag = (u1 < 0x7f800000u) ? 1u : 0u;
    }
    __syncthreads();

    // -------- pass B: ray-b (dfb), only if ray-a missed (block-uniform) ---
    if (hflag == 0u) {
        float tbb = INF;
        for (int fi = tid; fi < F; fi += 256) {
            const float4 A = *(const float4*)(tri + (size_t)fi * 12);
            const float4 B = *(const float4*)(tri + (size_t)fi * 12 + 4);
            const float4 C = *(const float4*)(tri + (size_t)fi * 12 + 8);
            float e1x = A.w, e1y = B.x, e1z = B.y;
            float e2x = B.z, e2y = B.w, e2z = C.x;

            // identical expressions/order as pass A => identical bits
            float tvx = xx - A.x;
            float tvy = xy - A.y;
            float tvz = xz - A.z;
            float qx = (tvy * e1z) - (tvz * e1y);
            float qy = (tvz * e1x) - (tvx * e1z);
            float qz = (tvx * e1y) - (tvy * e1x);
            float tq = ((e2x * qx) + (e2y * qy)) + (e2z * qz);

            float px = (dby * e2z) - (dbz * e2y);
            float py = (dbz * e2x) - (dbx * e2z);
            float pz = (dbx * e2y) - (dby * e2x);
            float det = ((e1x * px) + (e1y * py)) + (e1z * pz);
            bool ok = fabsf(det) > EPSF;
            float inv = ok ? (1.0f / det) : 0.0f;
            float u = (((tvx * px) + (tvy * py)) + (tvz * pz)) * inv;
            float v = (((dbx * qx) + (dby * qy)) + (dbz * qz)) * inv;
            float t = tq * inv;
            bool valid = ok && (u >= -M) && (v >= -M) && ((u + v) <= 1.0f + M) && (t > EPSF);
            tbb = (valid && t < tbb) ? t : tbb;
        }
        unsigned int mb = __float_as_uint(tbb);
#pragma unroll
        for (int s = 1; s < 64; s <<= 1) {
            unsigned int ob = __shfl_xor(mb, s, 64);
            if (ob < mb) mb = ob;
        }
        if (lane == 0) red[wave] = mb;
        __syncthreads();
        if (tid == 0)
            u2s = min(min(red[0], red[1]), min(red[2], red[3]));
    }

    // -------- finalize (verbatim), thread 0 --------
    if (tid != 0) return;
    float t1 = __uint_as_float(u1s);
    bool h1 = t1 < INF;
    float t2 = h1 ? INF : __uint_as_float(u2s);
    bool h2 = t2 < INF;

    float xcx, xcy, xcz;
    if (h1) {
        xcx = xx + ((-ncx) * t1);
        xcy = xy + ((-ncy) * t1);
        xcz = xz + ((-ncz) * t1);
    } else if (h2) {
        xcx = xx + (dbx * t2);
        xcy = xy + (dby * t2);
        xcz = xz + (dbz * t2);
    } else {
        xcx = v1w[p * 3 + 0]; xcy = v1w[p * 3 + 1]; xcz = v1w[p * 3 + 2];
    }
    float s = (((xx - xcx) * ncx) + ((xy - xcy) * ncy)) + ((xz - xcz) * ncz);

    out[p * 3 + 0] = xcx;
    out[p * 3 + 1] = xcy;
    out[p * 3 + 2] = xcz;
    out[3 * N + p] = s;
    out[4 * N + p * 3 + 0] = ncx;
    out[4 * N + p * 3 + 1] = ncy;
    out[4 * N + p * 3 + 2] = ncz;
}

// ---------------------------------------------------------------------------
extern "C" void kernel_launch(void* const* d_in, const int* in_sizes, int n_in,
                              void* d_out, int out_size, void* d_ws, size_t ws_size,
                              hipStream_t stream) {
    const float* x     = (const float*)d_in[0];
    const float* verts = (const float*)d_in[1];
    const float* vnorm = (const float*)d_in[2];
    const int*   faces = (const int*)d_in[3];
    int N = in_sizes[0] / 3;
    int V = in_sizes[1] / 3;
    int F = in_sizes[3] / 3;

    float* tri  = (float*)d_ws;          // F*12 floats (16B-aligned AoS)
    float* ncw  = tri + (size_t)F * 12;  // 3*N
    float* v1w  = ncw + 3 * N;           // 3*N
    float* dfbw = v1w + 3 * N;           // 3*N

    hipLaunchKernelGGL(knn_prep_kernel, dim3(N), dim3(256), 0, stream,
                       x, verts, vnorm, faces, tri, ncw, v1w, dfbw, N, V, F);
    hipLaunchKernelGGL(ray_fin_kernel, dim3(N), dim3(256), 0, stream,
                       x, tri, ncw, v1w, dfbw, (float*)d_out, N, F);
}